// Round 1
// baseline (155.491 us; speedup 1.0000x reference)
//
#include <hip/hip_runtime.h>

typedef __attribute__((ext_vector_type(8))) short bf16x8;
typedef __attribute__((ext_vector_type(4))) float f32x4;
typedef __attribute__((ext_vector_type(4))) unsigned short u16x4;

__device__ __forceinline__ unsigned short f2bf(float f) {
  union { float f; unsigned u; } v; v.f = f;
  unsigned r = v.u + 0x7FFFu + ((v.u >> 16) & 1u);
  return (unsigned short)(r >> 16);
}

// ---------------- conv1x1: Y[o][n] = sum_k W[o][k] * X[k][n] ----------------
// X: [128][4096] f32, W: [OC][128] f32, Y: [OC][4096] f32.
// qkv_mode=1: blockIdx.z = j in {0,1,2}; X = (j==0 ? Xq : Xkv), W += j*128*128,
// Y += j*128*4096.  qkv_mode=0: single GEMM (proj).
__global__ __launch_bounds__(256)
void conv1x1_kernel(const float* __restrict__ Xq, const float* __restrict__ Xkv,
                    const float* __restrict__ W, float* __restrict__ Y, int qkv_mode)
{
  __shared__ __align__(16) float Xl[128][64];
  __shared__ __align__(16) float Wl[128][64];  // transposed: Wl[k][o]
  const int t = threadIdx.x;
  const int j = qkv_mode ? (int)blockIdx.z : 0;
  const float* X = (qkv_mode && j > 0) ? Xkv : Xq;
  const float* Wb = W + j * (128 * 128);
  float* Yb = Y + j * (128 * 4096);
  const int n0 = blockIdx.x * 64;
  const int o0 = blockIdx.y * 64;
  const int tx = t & 15, ty = t >> 4;

  // stage X tile [128 k][64 n]
  #pragma unroll
  for (int i = 0; i < 8; ++i) {
    int row = i * 16 + ty;
    *(f32x4*)&Xl[row][tx * 4] = *(const f32x4*)(X + row * 4096 + n0 + tx * 4);
  }
  // stage W tile transposed -> Wl[k][o]
  #pragma unroll
  for (int i = 0; i < 8; ++i) {
    int idx = i * 256 + t;
    int o = idx >> 5, k4 = idx & 31;
    f32x4 v = *(const f32x4*)(Wb + (o0 + o) * 128 + k4 * 4);
    Wl[k4 * 4 + 0][o] = v[0];
    Wl[k4 * 4 + 1][o] = v[1];
    Wl[k4 * 4 + 2][o] = v[2];
    Wl[k4 * 4 + 3][o] = v[3];
  }
  __syncthreads();

  float acc[4][4] = {};
  #pragma unroll 8
  for (int k = 0; k < 128; ++k) {
    f32x4 a = *(const f32x4*)&Xl[k][tx * 4];
    f32x4 b = *(const f32x4*)&Wl[k][ty * 4];
    #pragma unroll
    for (int q = 0; q < 4; ++q)
      #pragma unroll
      for (int r = 0; r < 4; ++r)
        acc[q][r] = fmaf(b[q], a[r], acc[q][r]);
  }
  #pragma unroll
  for (int q = 0; q < 4; ++q) {
    f32x4 v; v[0] = acc[q][0]; v[1] = acc[q][1]; v[2] = acc[q][2]; v[3] = acc[q][3];
    *(f32x4*)(Yb + (o0 + ty * 4 + q) * 4096 + n0 + tx * 4) = v;
  }
}

// ------------- depthwise 3x3 SAME on one 64x64 plane per block -------------
// In: T [384][4096] f32.  Out: Qb [384][4096] bf16 (ushort bits).
// Temperature (per head) is folded into the q channels (jc < 128).
__global__ __launch_bounds__(256)
void dwconv_kernel(const float* __restrict__ T, const float* __restrict__ Wd,
                   const float* __restrict__ temp, unsigned short* __restrict__ Qb)
{
  __shared__ __align__(16) float P[4096];
  const int jc = blockIdx.x;   // 0..383
  const int t = threadIdx.x;
  const float* in = T + jc * 4096;
  #pragma unroll
  for (int i = 0; i < 4; ++i)
    *(f32x4*)&P[(i * 256 + t) * 4] = *(const f32x4*)&in[(i * 256 + t) * 4];
  float w[9];
  #pragma unroll
  for (int k = 0; k < 9; ++k) w[k] = Wd[jc * 9 + k];
  const float scale = (jc < 128) ? temp[jc >> 5] : 1.0f;
  __syncthreads();
  unsigned short* out = Qb + jc * 4096;
  #pragma unroll 4
  for (int i = 0; i < 16; ++i) {
    int idx = i * 256 + t;
    int y = idx >> 6, x = idx & 63;
    float acc = 0.f;
    #pragma unroll
    for (int dy = -1; dy <= 1; ++dy) {
      int yy = y + dy;
      if (yy < 0 || yy > 63) continue;
      #pragma unroll
      for (int dx = -1; dx <= 1; ++dx) {
        int xx = x + dx;
        if (xx < 0 || xx > 63) continue;
        acc += w[(dy + 1) * 3 + (dx + 1)] * P[yy * 64 + xx];
      }
    }
    out[idx] = f2bf(acc * scale);
  }
}

// ----------------------- flash attention (bf16 MFMA) -----------------------
// Qb layout: [3][128][4096] bf16, channel = h*32 + d.
// Per block: head h (blockIdx.y), 64 queries (blockIdx.x*64). 4 waves, 16 q each.
// S = Q K^T via mfma_f32_16x16x32_bf16 (K-dim 32 == head_dim), online softmax,
// O += P V via MFMA.  Output: O[h*32+d][n] f32.
#define KOFF (128 * 4096)
#define VOFF (256 * 4096)

__global__ __launch_bounds__(256)
void attn_kernel(const unsigned short* __restrict__ Qb, float* __restrict__ O)
{
  __shared__ __align__(16) unsigned short Kl[128][40];   // [m][d] transposed
  __shared__ __align__(16) unsigned short Vl[32][136];   // [d][m] natural
  __shared__ __align__(16) unsigned short Pl[4][16][40]; // per-wave P [n][m]
  const int t = threadIdx.x;
  const int w = t >> 6, l = t & 63, g = l >> 4, c = l & 15;
  const int h = blockIdx.y;
  const int nb = blockIdx.x * 64 + w * 16;

  // Q A-fragment: lane holds Q[n = nb + c][d = 8g + e]
  bf16x8 qf;
  #pragma unroll
  for (int e = 0; e < 8; ++e)
    qf[e] = (short)Qb[(h * 32 + g * 8 + e) * 4096 + nb + c];

  f32x4 o0 = {0.f, 0.f, 0.f, 0.f}, o1 = {0.f, 0.f, 0.f, 0.f};
  float mrun[4], lrun[4];
  #pragma unroll
  for (int r = 0; r < 4; ++r) { mrun[r] = -1e30f; lrun[r] = 0.f; }

  const int td = t >> 3;        // 0..31: d for staging
  const int tm = (t & 7) * 4;   // m within a 32-chunk

  for (int m0 = 0; m0 < 4096; m0 += 128) {
    __syncthreads();
    // stage K (transposed) and V (natural) for 128 keys
    #pragma unroll
    for (int mm = 0; mm < 4; ++mm) {
      int m = mm * 32 + tm;
      u16x4 kv = *(const u16x4*)&Qb[KOFF + (h * 32 + td) * 4096 + m0 + m];
      Kl[m + 0][td] = kv[0];
      Kl[m + 1][td] = kv[1];
      Kl[m + 2][td] = kv[2];
      Kl[m + 3][td] = kv[3];
      *(u16x4*)&Vl[td][m] = *(const u16x4*)&Qb[VOFF + (h * 32 + td) * 4096 + m0 + m];
    }
    __syncthreads();

    #pragma unroll
    for (int sub = 0; sub < 4; ++sub) {
      const int mb = sub * 32;
      bf16x8 kf0 = *(const bf16x8*)&Kl[mb + c][g * 8];
      bf16x8 kf1 = *(const bf16x8*)&Kl[mb + 16 + c][g * 8];
      f32x4 z = {0.f, 0.f, 0.f, 0.f};
      f32x4 s0 = __builtin_amdgcn_mfma_f32_16x16x32_bf16(qf, kf0, z, 0, 0, 0);
      f32x4 s1 = __builtin_amdgcn_mfma_f32_16x16x32_bf16(qf, kf1, z, 0, 0, 0);

      // row max over the 32 keys (16 lanes x 2 halves)
      float tmx[4];
      #pragma unroll
      for (int r = 0; r < 4; ++r) tmx[r] = fmaxf(s0[r], s1[r]);
      #pragma unroll
      for (int mask = 1; mask < 16; mask <<= 1)
        #pragma unroll
        for (int r = 0; r < 4; ++r)
          tmx[r] = fmaxf(tmx[r], __shfl_xor(tmx[r], mask, 64));

      float p0[4], p1[4], psum[4];
      #pragma unroll
      for (int r = 0; r < 4; ++r) {
        float mnew = fmaxf(mrun[r], tmx[r]);
        float sc = __expf(mrun[r] - mnew);
        p0[r] = __expf(s0[r] - mnew);
        p1[r] = __expf(s1[r] - mnew);
        psum[r] = p0[r] + p1[r];
        lrun[r] *= sc;
        mrun[r] = mnew;
        o0[r] *= sc; o1[r] *= sc;
      }
      #pragma unroll
      for (int mask = 1; mask < 16; mask <<= 1)
        #pragma unroll
        for (int r = 0; r < 4; ++r)
          psum[r] += __shfl_xor(psum[r], mask, 64);
      #pragma unroll
      for (int r = 0; r < 4; ++r) lrun[r] += psum[r];

      // P (bf16) -> per-wave LDS, re-read in A-fragment layout
      #pragma unroll
      for (int r = 0; r < 4; ++r) {
        Pl[w][g * 4 + r][c] = f2bf(p0[r]);
        Pl[w][g * 4 + r][16 + c] = f2bf(p1[r]);
      }
      bf16x8 pf = *(const bf16x8*)&Pl[w][c][g * 8];
      bf16x8 vf0 = *(const bf16x8*)&Vl[c][mb + g * 8];
      bf16x8 vf1 = *(const bf16x8*)&Vl[16 + c][mb + g * 8];
      o0 = __builtin_amdgcn_mfma_f32_16x16x32_bf16(pf, vf0, o0, 0, 0, 0);
      o1 = __builtin_amdgcn_mfma_f32_16x16x32_bf16(pf, vf1, o1, 0, 0, 0);
    }
  }

  // epilogue: normalize and write O[h*32+d][n]
  #pragma unroll
  for (int r = 0; r < 4; ++r) {
    float inv = 1.0f / lrun[r];
    int n = nb + g * 4 + r;
    O[(h * 32 + c) * 4096 + n] = o0[r] * inv;
    O[(h * 32 + 16 + c) * 4096 + n] = o1[r] * inv;
  }
}

extern "C" void kernel_launch(void* const* d_in, const int* in_sizes, int n_in,
                              void* d_out, int out_size, void* d_ws, size_t ws_size,
                              hipStream_t stream) {
  const float* xq    = (const float*)d_in[0];
  const float* xkv   = (const float*)d_in[1];
  const float* wqkv  = (const float*)d_in[2];
  const float* wdw   = (const float*)d_in[3];
  const float* wproj = (const float*)d_in[4];
  const float* temp  = (const float*)d_in[5];
  float* out = (float*)d_out;

  char* ws = (char*)d_ws;
  float* t_pre            = (float*)ws;                    // 3*128*4096 f32 = 6 MB
  unsigned short* qb      = (unsigned short*)(ws + 6291456); // 3*128*4096 bf16 = 3 MB
  float* attn_out         = (float*)(ws + 9437184);        // 128*4096 f32 = 2 MB

  // 1) qkv 1x1 conv (3 GEMMs: q from x_q, k/v from x_kv)
  conv1x1_kernel<<<dim3(64, 2, 3), 256, 0, stream>>>(xq, xkv, wqkv, t_pre, 1);
  // 2) depthwise 3x3 + bf16 cast (+ temperature folded into q)
  dwconv_kernel<<<dim3(384), 256, 0, stream>>>(t_pre, wdw, temp, qb);
  // 3) flash attention
  attn_kernel<<<dim3(64, 4), 256, 0, stream>>>(qb, attn_out);
  // 4) proj 1x1 conv
  conv1x1_kernel<<<dim3(64, 2, 1), 256, 0, stream>>>(attn_out, nullptr, wproj, out, 0);
}

// Round 2
// 65.665 us; speedup vs baseline: 2.3679x; 2.3679x over previous
//
#include <hip/hip_runtime.h>

typedef short bf16x4 __attribute__((ext_vector_type(4)));
typedef short bf16x8 __attribute__((ext_vector_type(8)));
typedef float f32x4 __attribute__((ext_vector_type(4)));
typedef unsigned short u16x4 __attribute__((ext_vector_type(4)));
typedef unsigned short u16x8 __attribute__((ext_vector_type(8)));

__device__ __forceinline__ unsigned short f2bf(float f) {
  union { float f; unsigned u; } v; v.f = f;
  unsigned r = v.u + 0x7FFFu + ((v.u >> 16) & 1u);
  return (unsigned short)(r >> 16);
}
__device__ __forceinline__ unsigned fbits(float f) {
  union { float f; unsigned u; } x; x.f = f; return x.u;
}
__device__ __forceinline__ float bfloat(unsigned u) {
  union { unsigned u; float f; } x; x.u = u; return x.f;
}
__device__ __forceinline__ float fexp2(float x) {
#if __has_builtin(__builtin_amdgcn_exp2f)
  return __builtin_amdgcn_exp2f(x);
#else
  return exp2f(x);
#endif
}
__device__ __forceinline__ f32x4 pv_mfma(bf16x4 a, bf16x4 b, f32x4 c) {
#if __has_builtin(__builtin_amdgcn_mfma_f32_16x16x16bf16_1k)
  return __builtin_amdgcn_mfma_f32_16x16x16bf16_1k(a, b, c, 0, 0, 0);
#else
  // zero-pad to K=32; k-position mapping of zeros is consistent between A and B
  bf16x8 az = {a[0], a[1], a[2], a[3], 0, 0, 0, 0};
  bf16x8 bz = {b[0], b[1], b[2], b[3], 0, 0, 0, 0};
  return __builtin_amdgcn_mfma_f32_16x16x32_bf16(az, bz, c, 0, 0, 0);
#endif
}

// ---------------- conv1x1: Y[o][n] = sum_k W[o][k] * X[k][n] ----------------
__global__ __launch_bounds__(256)
void conv1x1_kernel(const float* __restrict__ Xq, const float* __restrict__ Xkv,
                    const float* __restrict__ W, float* __restrict__ Y, int qkv_mode)
{
  __shared__ __align__(16) float Xl[128][64];
  __shared__ __align__(16) float Wl[128][64];  // transposed: Wl[k][o]
  const int t = threadIdx.x;
  const int j = qkv_mode ? (int)blockIdx.z : 0;
  const float* X = (qkv_mode && j > 0) ? Xkv : Xq;
  const float* Wb = W + j * (128 * 128);
  float* Yb = Y + j * (128 * 4096);
  const int n0 = blockIdx.x * 64;
  const int o0 = blockIdx.y * 64;
  const int tx = t & 15, ty = t >> 4;

  #pragma unroll
  for (int i = 0; i < 8; ++i) {
    int row = i * 16 + ty;
    *(f32x4*)&Xl[row][tx * 4] = *(const f32x4*)(X + row * 4096 + n0 + tx * 4);
  }
  #pragma unroll
  for (int i = 0; i < 8; ++i) {
    int idx = i * 256 + t;
    int o = idx >> 5, k4 = idx & 31;
    f32x4 v = *(const f32x4*)(Wb + (o0 + o) * 128 + k4 * 4);
    Wl[k4 * 4 + 0][o] = v[0];
    Wl[k4 * 4 + 1][o] = v[1];
    Wl[k4 * 4 + 2][o] = v[2];
    Wl[k4 * 4 + 3][o] = v[3];
  }
  __syncthreads();

  float acc[4][4] = {};
  #pragma unroll 8
  for (int k = 0; k < 128; ++k) {
    f32x4 a = *(const f32x4*)&Xl[k][tx * 4];
    f32x4 b = *(const f32x4*)&Wl[k][ty * 4];
    #pragma unroll
    for (int q = 0; q < 4; ++q)
      #pragma unroll
      for (int r = 0; r < 4; ++r)
        acc[q][r] = fmaf(b[q], a[r], acc[q][r]);
  }
  #pragma unroll
  for (int q = 0; q < 4; ++q) {
    f32x4 v; v[0] = acc[q][0]; v[1] = acc[q][1]; v[2] = acc[q][2]; v[3] = acc[q][3];
    *(f32x4*)(Yb + (o0 + ty * 4 + q) * 4096 + n0 + tx * 4) = v;
  }
}

// ------------- depthwise 3x3 SAME on one 64x64 plane per block -------------
// Temperature * log2(e) folded into q channels so attention can use exp2.
__global__ __launch_bounds__(256)
void dwconv_kernel(const float* __restrict__ T, const float* __restrict__ Wd,
                   const float* __restrict__ temp, unsigned short* __restrict__ Qb)
{
  __shared__ __align__(16) float P[4096];
  const int jc = blockIdx.x;   // 0..383
  const int t = threadIdx.x;
  const float* in = T + jc * 4096;
  #pragma unroll
  for (int i = 0; i < 4; ++i)
    *(f32x4*)&P[(i * 256 + t) * 4] = *(const f32x4*)&in[(i * 256 + t) * 4];
  float w[9];
  #pragma unroll
  for (int k = 0; k < 9; ++k) w[k] = Wd[jc * 9 + k];
  const float scale = (jc < 128) ? temp[jc >> 5] * 1.4426950408889634f : 1.0f;
  __syncthreads();
  unsigned short* out = Qb + jc * 4096;
  #pragma unroll 4
  for (int i = 0; i < 16; ++i) {
    int idx = i * 256 + t;
    int y = idx >> 6, x = idx & 63;
    float acc = 0.f;
    #pragma unroll
    for (int dy = -1; dy <= 1; ++dy) {
      int yy = y + dy;
      if (yy < 0 || yy > 63) continue;
      #pragma unroll
      for (int dx = -1; dx <= 1; ++dx) {
        int xx = x + dx;
        if (xx < 0 || xx > 63) continue;
        acc += w[(dy + 1) * 3 + (dx + 1)] * P[yy * 64 + xx];
      }
    }
    out[idx] = f2bf(acc * scale);
  }
}

// ----------------------- flash attention (bf16 MFMA) -----------------------
// S^T = mfma(K-frag, Q-frag): lane (c,g) holds S^T[key=4g+r][q=c] -> its 4
// values ARE the B-frag of a 16x16x16 PV MFMA (P stays in registers).
// No max subtraction (logits are small); p = exp2(s) since temp*log2e was
// folded into Q. 4 in-block key-split groups x 4 q-waves = 1024 threads.
#define KOFF (128 * 4096)
#define VOFF (256 * 4096)
#define KSTR 36
#define VSTR 132

__global__ __launch_bounds__(1024, 4)
void attn_kernel(const unsigned short* __restrict__ Qb, float* __restrict__ O)
{
  __shared__ __align__(16) char lds[70656];
  unsigned short* Kg = (unsigned short*)lds;             // [4][128][36] u16
  unsigned short* Vg = (unsigned short*)(lds + 36864);   // [4][32][132] u16
  const int t = threadIdx.x;
  const int g4 = t >> 8;          // key-split group 0..3
  const int ts = t & 255;         // thread within group
  const int qw = (t >> 6) & 3;    // q-wave within group
  const int l = t & 63;
  const int c = l & 15, g = l >> 4;
  const int h = blockIdx.y;
  const int nq = blockIdx.x * 64 + qw * 16;

  unsigned short* Kgg = Kg + g4 * (128 * KSTR);
  unsigned short* Vgg = Vg + g4 * (32 * VSTR);

  // Q B-fragment: lane holds Q[d = 8g + e][n = nq + c]
  bf16x8 qf;
  #pragma unroll
  for (int e = 0; e < 8; ++e)
    qf[e] = (short)Qb[(h * 32 + g * 8 + e) * 4096 + nq + c];

  f32x4 oh0 = {0.f, 0.f, 0.f, 0.f}, oh1 = {0.f, 0.f, 0.f, 0.f};
  float lsum = 0.f;

  const int kdp = ts >> 4;        // d-pair 0..15 for K staging
  const int kj  = ts & 15;        // m-quad
  const int vdd = ts >> 4;        // d 0..15 for V staging
  const int vj  = ts & 15;        // m-octet

  // prefetch tile 0 into registers
  u16x4 kr0[2], kr1[2];
  u16x8 vr[2];
  {
    const int m0 = g4 * 128;
    #pragma unroll
    for (int it = 0; it < 2; ++it) {
      int m = kj * 4 + it * 64;
      kr0[it] = *(const u16x4*)&Qb[KOFF + (h * 32 + 2 * kdp) * 4096 + m0 + m];
      kr1[it] = *(const u16x4*)&Qb[KOFF + (h * 32 + 2 * kdp + 1) * 4096 + m0 + m];
      vr[it] = *(const u16x8*)&Qb[VOFF + (h * 32 + vdd + 16 * it) * 4096 + m0 + vj * 8];
    }
  }

  for (int tt = 0; tt < 8; ++tt) {
    __syncthreads();   // previous tile's compute done; LDS free
    // write staged registers to LDS
    #pragma unroll
    for (int it = 0; it < 2; ++it) {
      int m = kj * 4 + it * 64;
      #pragma unroll
      for (int i = 0; i < 4; ++i)
        *(unsigned*)&Kgg[(m + i) * KSTR + 2 * kdp] =
            (unsigned)kr0[it][i] | ((unsigned)kr1[it][i] << 16);
      int d = vdd + 16 * it;
      *(u16x4*)&Vgg[d * VSTR + vj * 8] =
          __builtin_shufflevector(vr[it], vr[it], 0, 1, 2, 3);
      *(u16x4*)&Vgg[d * VSTR + vj * 8 + 4] =
          __builtin_shufflevector(vr[it], vr[it], 4, 5, 6, 7);
    }
    __syncthreads();
    // prefetch next tile
    if (tt < 7) {
      const int m0n = ((tt + 1) * 4 + g4) * 128;
      #pragma unroll
      for (int it = 0; it < 2; ++it) {
        int m = kj * 4 + it * 64;
        kr0[it] = *(const u16x4*)&Qb[KOFF + (h * 32 + 2 * kdp) * 4096 + m0n + m];
        kr1[it] = *(const u16x4*)&Qb[KOFF + (h * 32 + 2 * kdp + 1) * 4096 + m0n + m];
        vr[it] = *(const u16x8*)&Qb[VOFF + (h * 32 + vdd + 16 * it) * 4096 + m0n + vj * 8];
      }
    }
    // compute on staged tile: 8 chunks of 16 keys
    #pragma unroll
    for (int j = 0; j < 8; ++j) {
      bf16x4 klo = *(const bf16x4*)&Kgg[(j * 16 + c) * KSTR + g * 8];
      bf16x4 khi = *(const bf16x4*)&Kgg[(j * 16 + c) * KSTR + g * 8 + 4];
      bf16x8 kf = __builtin_shufflevector(klo, khi, 0, 1, 2, 3, 4, 5, 6, 7);
      f32x4 z = {0.f, 0.f, 0.f, 0.f};
      f32x4 s = __builtin_amdgcn_mfma_f32_16x16x32_bf16(kf, qf, z, 0, 0, 0);

      unsigned u0 = fbits(fexp2(s[0]));
      unsigned u1 = fbits(fexp2(s[1]));
      unsigned u2 = fbits(fexp2(s[2]));
      unsigned u3 = fbits(fexp2(s[3]));
      unsigned t0 = u0 & 0xFFFF0000u, t1 = u1 & 0xFFFF0000u;
      unsigned t2 = u2 & 0xFFFF0000u, t3 = u3 & 0xFFFF0000u;
      // lsum from truncated values so numerator/denominator bias cancels
      lsum += (bfloat(t0) + bfloat(t1)) + (bfloat(t2) + bfloat(t3));
      unsigned pk0 = (u0 >> 16) | t1;
      unsigned pk1 = (u2 >> 16) | t3;
      union { unsigned u[2]; bf16x4 v; } pu;
      pu.u[0] = pk0; pu.u[1] = pk1;

      bf16x4 vf0 = *(const bf16x4*)&Vgg[c * VSTR + j * 16 + g * 4];
      bf16x4 vf1 = *(const bf16x4*)&Vgg[(16 + c) * VSTR + j * 16 + g * 4];
      oh0 = pv_mfma(vf0, pu.v, oh0);
      oh1 = pv_mfma(vf1, pu.v, oh1);
    }
  }

  // final per-query sum over the 4 lane-groups
  lsum += __shfl_xor(lsum, 16, 64);
  lsum += __shfl_xor(lsum, 32, 64);

  __syncthreads();
  // overlay partial buffers on the staging LDS
  float* Of = (float*)lds;                 // [4][32][66]
  float* lf = (float*)(lds + 36864);       // [4][64]
  #pragma unroll
  for (int r = 0; r < 4; ++r) {
    Of[(g4 * 32 + 4 * g + r) * 66 + qw * 16 + c]      = oh0[r];
    Of[(g4 * 32 + 16 + 4 * g + r) * 66 + qw * 16 + c] = oh1[r];
  }
  if (l < 16) lf[g4 * 64 + qw * 16 + c] = lsum;
  __syncthreads();

  #pragma unroll
  for (int e = t; e < 2048; e += 1024) {
    int d = e >> 6, q = e & 63;
    float s4 = Of[(0 * 32 + d) * 66 + q] + Of[(1 * 32 + d) * 66 + q] +
               Of[(2 * 32 + d) * 66 + q] + Of[(3 * 32 + d) * 66 + q];
    float li = lf[q] + lf[64 + q] + lf[128 + q] + lf[192 + q];
    O[(h * 32 + d) * 4096 + blockIdx.x * 64 + q] = s4 / li;
  }
}

extern "C" void kernel_launch(void* const* d_in, const int* in_sizes, int n_in,
                              void* d_out, int out_size, void* d_ws, size_t ws_size,
                              hipStream_t stream) {
  const float* xq    = (const float*)d_in[0];
  const float* xkv   = (const float*)d_in[1];
  const float* wqkv  = (const float*)d_in[2];
  const float* wdw   = (const float*)d_in[3];
  const float* wproj = (const float*)d_in[4];
  const float* temp  = (const float*)d_in[5];
  float* out = (float*)d_out;

  char* ws = (char*)d_ws;
  float* t_pre       = (float*)ws;                         // 3*128*4096 f32 = 6 MB
  unsigned short* qb = (unsigned short*)(ws + 6291456);    // 3*128*4096 bf16 = 3 MB
  float* attn_out    = (float*)(ws + 9437184);             // 128*4096 f32 = 2 MB

  conv1x1_kernel<<<dim3(64, 2, 3), 256, 0, stream>>>(xq, xkv, wqkv, t_pre, 1);
  dwconv_kernel<<<dim3(384), 256, 0, stream>>>(t_pre, wdw, temp, qb);
  attn_kernel<<<dim3(64, 4), 1024, 0, stream>>>(qb, attn_out);
  conv1x1_kernel<<<dim3(64, 2, 1), 256, 0, stream>>>(attn_out, nullptr, wproj, out, 0);
}

// Round 3
// 60.744 us; speedup vs baseline: 2.5598x; 1.0810x over previous
//
#include <hip/hip_runtime.h>

typedef short bf16x4 __attribute__((ext_vector_type(4)));
typedef short bf16x8 __attribute__((ext_vector_type(8)));
typedef float f32x4 __attribute__((ext_vector_type(4)));
typedef unsigned short u16x4 __attribute__((ext_vector_type(4)));
typedef unsigned short u16x8 __attribute__((ext_vector_type(8)));

__device__ __forceinline__ unsigned short f2bf(float f) {
  union { float f; unsigned u; } v; v.f = f;
  unsigned r = v.u + 0x7FFFu + ((v.u >> 16) & 1u);
  return (unsigned short)(r >> 16);
}
__device__ __forceinline__ unsigned fbits(float f) {
  union { float f; unsigned u; } x; x.f = f; return x.u;
}
__device__ __forceinline__ float bfloat(unsigned u) {
  union { unsigned u; float f; } x; x.u = u; return x.f;
}
__device__ __forceinline__ float fexp2(float x) {
#if __has_builtin(__builtin_amdgcn_exp2f)
  return __builtin_amdgcn_exp2f(x);
#else
  return exp2f(x);
#endif
}
__device__ __forceinline__ f32x4 pv_mfma(bf16x4 a, bf16x4 b, f32x4 c) {
#if __has_builtin(__builtin_amdgcn_mfma_f32_16x16x16bf16_1k)
  return __builtin_amdgcn_mfma_f32_16x16x16bf16_1k(a, b, c, 0, 0, 0);
#else
  bf16x8 az = {a[0], a[1], a[2], a[3], 0, 0, 0, 0};
  bf16x8 bz = {b[0], b[1], b[2], b[3], 0, 0, 0, 0};
  return __builtin_amdgcn_mfma_f32_16x16x32_bf16(az, bz, c, 0, 0, 0);
#endif
}

// ---------- cast/transpose: Xq,Xkv [128][4096] f32 -> XT [2][4096][128] bf16,
// ---------- plus weight casts (wqkv -> bf16, wproj -> hi/lo bf16 split).
__global__ __launch_bounds__(256)
void cast_kernel(const float* __restrict__ Xq, const float* __restrict__ Xkv,
                 const float* __restrict__ Wqkv, const float* __restrict__ Wproj,
                 unsigned short* __restrict__ XT, unsigned short* __restrict__ Wq16,
                 unsigned short* __restrict__ Wph, unsigned short* __restrict__ Wpl)
{
  const int b = blockIdx.x, t = threadIdx.x;
  if (b < 256) {
    __shared__ __align__(16) float Tl[64][68];
    const int img = b >> 7, kt = (b >> 6) & 1, nt = b & 63;
    const float* X = img ? Xkv : Xq;
    #pragma unroll
    for (int i = 0; i < 4; ++i) {
      int e = i * 256 + t;
      int r = e >> 4, c4 = (e & 15) * 4;
      *(f32x4*)&Tl[r][c4] = *(const f32x4*)&X[(kt * 64 + r) * 4096 + nt * 64 + c4];
    }
    __syncthreads();
    unsigned short* out = XT + img * (4096 * 128);
    #pragma unroll
    for (int i = 0; i < 2; ++i) {
      int u = i * 256 + t;
      int n = u >> 3, kg = u & 7;
      u16x8 tv;
      #pragma unroll
      for (int j = 0; j < 8; ++j) tv[j] = f2bf(Tl[kg * 8 + j][n]);
      *(u16x8*)&out[(nt * 64 + n) * 128 + kt * 64 + kg * 8] = tv;
    }
  } else {
    const int wb = b - 256;
    if (wb < 3) {
      #pragma unroll 4
      for (int i = 0; i < 64; ++i) {
        int idx = wb * 16384 + i * 256 + t;
        Wq16[idx] = f2bf(Wqkv[idx]);
      }
    } else {
      #pragma unroll 4
      for (int i = 0; i < 64; ++i) {
        int idx = i * 256 + t;
        float v = Wproj[idx];
        unsigned short h = f2bf(v);
        float hf = bfloat((unsigned)h << 16);
        Wph[idx] = h;
        Wpl[idx] = f2bf(v - hf);
      }
    }
  }
}

// ---------- qkv GEMM: Y[o][n] = sum_k Wq16[o][k] * X[k][n], all-register MFMA.
// A-frag: Wq16[(o)(K-major)], B-frag: XT[n][k] (K-major). No LDS, no barriers.
__global__ __launch_bounds__(256)
void gemm_qkv_kernel(const unsigned short* __restrict__ XT,
                     const unsigned short* __restrict__ Wq16, float* __restrict__ Y)
{
  const int t = threadIdx.x;
  const int w = t >> 6, c = t & 15, g = (t & 63) >> 4;
  const int n0 = blockIdx.x * 32;
  const int ob = blockIdx.y;                 // 0..5 (o-tile of 64); ob>=2 -> Xkv
  const int o_base = ob * 64 + w * 16;
  const unsigned short* B = XT + (ob >= 2 ? 4096 * 128 : 0);
  f32x4 acc0 = {0.f, 0.f, 0.f, 0.f}, acc1 = {0.f, 0.f, 0.f, 0.f};
  #pragma unroll
  for (int ks = 0; ks < 4; ++ks) {
    bf16x8 a = *(const bf16x8*)&Wq16[(o_base + c) * 128 + ks * 32 + g * 8];
    bf16x8 b0 = *(const bf16x8*)&B[(n0 + c) * 128 + ks * 32 + g * 8];
    bf16x8 b1 = *(const bf16x8*)&B[(n0 + 16 + c) * 128 + ks * 32 + g * 8];
    acc0 = __builtin_amdgcn_mfma_f32_16x16x32_bf16(a, b0, acc0, 0, 0, 0);
    acc1 = __builtin_amdgcn_mfma_f32_16x16x32_bf16(a, b1, acc1, 0, 0, 0);
  }
  #pragma unroll
  for (int i = 0; i < 4; ++i) {
    Y[(o_base + 4 * g + i) * 4096 + n0 + c] = acc0[i];
    Y[(o_base + 4 * g + i) * 4096 + n0 + 16 + c] = acc1[i];
  }
}

// ---------- proj GEMM, split-bf16 (hi+lo) for f32-quality output ----------
__global__ __launch_bounds__(256)
void gemm_proj_kernel(const unsigned short* __restrict__ Oth,
                      const unsigned short* __restrict__ Otl,
                      const unsigned short* __restrict__ Wph,
                      const unsigned short* __restrict__ Wpl, float* __restrict__ Y)
{
  const int t = threadIdx.x;
  const int w = t >> 6, c = t & 15, g = (t & 63) >> 4;
  const int n0 = blockIdx.x * 32;
  const int o_base = blockIdx.y * 64 + w * 16;
  f32x4 acc0 = {0.f, 0.f, 0.f, 0.f}, acc1 = {0.f, 0.f, 0.f, 0.f};
  #pragma unroll
  for (int ks = 0; ks < 4; ++ks) {
    const int ko = ks * 32 + g * 8;
    bf16x8 ah = *(const bf16x8*)&Wph[(o_base + c) * 128 + ko];
    bf16x8 al = *(const bf16x8*)&Wpl[(o_base + c) * 128 + ko];
    bf16x8 bh0 = *(const bf16x8*)&Oth[(n0 + c) * 128 + ko];
    bf16x8 bl0 = *(const bf16x8*)&Otl[(n0 + c) * 128 + ko];
    bf16x8 bh1 = *(const bf16x8*)&Oth[(n0 + 16 + c) * 128 + ko];
    bf16x8 bl1 = *(const bf16x8*)&Otl[(n0 + 16 + c) * 128 + ko];
    acc0 = __builtin_amdgcn_mfma_f32_16x16x32_bf16(al, bh0, acc0, 0, 0, 0);
    acc0 = __builtin_amdgcn_mfma_f32_16x16x32_bf16(ah, bl0, acc0, 0, 0, 0);
    acc0 = __builtin_amdgcn_mfma_f32_16x16x32_bf16(ah, bh0, acc0, 0, 0, 0);
    acc1 = __builtin_amdgcn_mfma_f32_16x16x32_bf16(al, bh1, acc1, 0, 0, 0);
    acc1 = __builtin_amdgcn_mfma_f32_16x16x32_bf16(ah, bl1, acc1, 0, 0, 0);
    acc1 = __builtin_amdgcn_mfma_f32_16x16x32_bf16(ah, bh1, acc1, 0, 0, 0);
  }
  #pragma unroll
  for (int i = 0; i < 4; ++i) {
    Y[(o_base + 4 * g + i) * 4096 + n0 + c] = acc0[i];
    Y[(o_base + 4 * g + i) * 4096 + n0 + 16 + c] = acc1[i];
  }
}

// ------------- depthwise 3x3 SAME on one 64x64 plane per block -------------
__global__ __launch_bounds__(256)
void dwconv_kernel(const float* __restrict__ T, const float* __restrict__ Wd,
                   const float* __restrict__ temp, unsigned short* __restrict__ Qb)
{
  __shared__ __align__(16) float P[4096];
  const int jc = blockIdx.x;
  const int t = threadIdx.x;
  const float* in = T + jc * 4096;
  #pragma unroll
  for (int i = 0; i < 4; ++i)
    *(f32x4*)&P[(i * 256 + t) * 4] = *(const f32x4*)&in[(i * 256 + t) * 4];
  float w[9];
  #pragma unroll
  for (int k = 0; k < 9; ++k) w[k] = Wd[jc * 9 + k];
  const float scale = (jc < 128) ? temp[jc >> 5] * 1.4426950408889634f : 1.0f;
  __syncthreads();
  unsigned short* out = Qb + jc * 4096;
  #pragma unroll 4
  for (int i = 0; i < 16; ++i) {
    int idx = i * 256 + t;
    int y = idx >> 6, x = idx & 63;
    float acc = 0.f;
    #pragma unroll
    for (int dy = -1; dy <= 1; ++dy) {
      int yy = y + dy;
      if (yy < 0 || yy > 63) continue;
      #pragma unroll
      for (int dx = -1; dx <= 1; ++dx) {
        int xx = x + dx;
        if (xx < 0 || xx > 63) continue;
        acc += w[(dy + 1) * 3 + (dx + 1)] * P[yy * 64 + xx];
      }
    }
    out[idx] = f2bf(acc * scale);
  }
}

// ----------------------- flash attention (bf16 MFMA) -----------------------
#define KOFF (128 * 4096)
#define VOFF (256 * 4096)
#define KSTR 40
#define VSTR 132

__global__ __launch_bounds__(1024, 4)
void attn_kernel(const unsigned short* __restrict__ Qb,
                 unsigned short* __restrict__ Oth, unsigned short* __restrict__ Otl)
{
  __shared__ __align__(16) char lds[74752];
  unsigned short* Kg = (unsigned short*)lds;             // [4][128][40] u16
  unsigned short* Vg = (unsigned short*)(lds + 40960);   // [4][32][132] u16
  const int t = threadIdx.x;
  const int g4 = t >> 8;
  const int ts = t & 255;
  const int qw = (t >> 6) & 3;
  const int l = t & 63;
  const int c = l & 15, g = l >> 4;
  const int h = blockIdx.y;
  const int nq = blockIdx.x * 64 + qw * 16;

  unsigned short* Kgg = Kg + g4 * (128 * KSTR);
  unsigned short* Vgg = Vg + g4 * (32 * VSTR);

  bf16x8 qf;
  #pragma unroll
  for (int e = 0; e < 8; ++e)
    qf[e] = (short)Qb[(h * 32 + g * 8 + e) * 4096 + nq + c];

  f32x4 oh0 = {0.f, 0.f, 0.f, 0.f}, oh1 = {0.f, 0.f, 0.f, 0.f};
  float lsum = 0.f;

  const int kdp = ts >> 4;
  const int kj  = ts & 15;
  const int vdd = ts >> 4;
  const int vj  = ts & 15;

  u16x4 kr0[2], kr1[2];
  u16x8 vr[2];
  {
    const int m0 = g4 * 128;
    #pragma unroll
    for (int it = 0; it < 2; ++it) {
      int m = kj * 4 + it * 64;
      kr0[it] = *(const u16x4*)&Qb[KOFF + (h * 32 + 2 * kdp) * 4096 + m0 + m];
      kr1[it] = *(const u16x4*)&Qb[KOFF + (h * 32 + 2 * kdp + 1) * 4096 + m0 + m];
      vr[it] = *(const u16x8*)&Qb[VOFF + (h * 32 + vdd + 16 * it) * 4096 + m0 + vj * 8];
    }
  }

  for (int tt = 0; tt < 8; ++tt) {
    __syncthreads();
    #pragma unroll
    for (int it = 0; it < 2; ++it) {
      int m = kj * 4 + it * 64;
      #pragma unroll
      for (int i = 0; i < 4; ++i)
        *(unsigned*)&Kgg[(m + i) * KSTR + 2 * kdp] =
            (unsigned)kr0[it][i] | ((unsigned)kr1[it][i] << 16);
      int d = vdd + 16 * it;
      *(u16x4*)&Vgg[d * VSTR + vj * 8] =
          __builtin_shufflevector(vr[it], vr[it], 0, 1, 2, 3);
      *(u16x4*)&Vgg[d * VSTR + vj * 8 + 4] =
          __builtin_shufflevector(vr[it], vr[it], 4, 5, 6, 7);
    }
    __syncthreads();
    if (tt < 7) {
      const int m0n = ((tt + 1) * 4 + g4) * 128;
      #pragma unroll
      for (int it = 0; it < 2; ++it) {
        int m = kj * 4 + it * 64;
        kr0[it] = *(const u16x4*)&Qb[KOFF + (h * 32 + 2 * kdp) * 4096 + m0n + m];
        kr1[it] = *(const u16x4*)&Qb[KOFF + (h * 32 + 2 * kdp + 1) * 4096 + m0n + m];
        vr[it] = *(const u16x8*)&Qb[VOFF + (h * 32 + vdd + 16 * it) * 4096 + m0n + vj * 8];
      }
    }
    #pragma unroll
    for (int j = 0; j < 8; ++j) {
      bf16x8 kf = *(const bf16x8*)&Kgg[(j * 16 + c) * KSTR + g * 8];
      f32x4 z = {0.f, 0.f, 0.f, 0.f};
      f32x4 s = __builtin_amdgcn_mfma_f32_16x16x32_bf16(kf, qf, z, 0, 0, 0);

      unsigned u0 = fbits(fexp2(s[0]));
      unsigned u1 = fbits(fexp2(s[1]));
      unsigned u2 = fbits(fexp2(s[2]));
      unsigned u3 = fbits(fexp2(s[3]));
      unsigned t0 = u0 & 0xFFFF0000u, t1 = u1 & 0xFFFF0000u;
      unsigned t2 = u2 & 0xFFFF0000u, t3 = u3 & 0xFFFF0000u;
      lsum += (bfloat(t0) + bfloat(t1)) + (bfloat(t2) + bfloat(t3));
      unsigned pk0 = (u0 >> 16) | t1;
      unsigned pk1 = (u2 >> 16) | t3;
      union { unsigned u[2]; bf16x4 v; } pu;
      pu.u[0] = pk0; pu.u[1] = pk1;

      bf16x4 vf0 = *(const bf16x4*)&Vgg[c * VSTR + j * 16 + g * 4];
      bf16x4 vf1 = *(const bf16x4*)&Vgg[(16 + c) * VSTR + j * 16 + g * 4];
      oh0 = pv_mfma(vf0, pu.v, oh0);
      oh1 = pv_mfma(vf1, pu.v, oh1);
    }
  }

  lsum += __shfl_xor(lsum, 16, 64);
  lsum += __shfl_xor(lsum, 32, 64);

  __syncthreads();
  float* Of = (float*)lds;                 // [4][32][66]
  float* lf = (float*)(lds + 36864);       // [4][64]
  #pragma unroll
  for (int r = 0; r < 4; ++r) {
    Of[(g4 * 32 + 4 * g + r) * 66 + qw * 16 + c]      = oh0[r];
    Of[(g4 * 32 + 16 + 4 * g + r) * 66 + qw * 16 + c] = oh1[r];
  }
  if (l < 16) lf[g4 * 64 + qw * 16 + c] = lsum;
  __syncthreads();

  #pragma unroll
  for (int e = t; e < 2048; e += 1024) {
    int d = e & 31, q = e >> 5;
    float s4 = Of[(0 * 32 + d) * 66 + q] + Of[(1 * 32 + d) * 66 + q] +
               Of[(2 * 32 + d) * 66 + q] + Of[(3 * 32 + d) * 66 + q];
    float li = lf[q] + lf[64 + q] + lf[128 + q] + lf[192 + q];
    float val = s4 / li;
    unsigned short hi = f2bf(val);
    float hf = bfloat((unsigned)hi << 16);
    int idx = (blockIdx.x * 64 + q) * 128 + h * 32 + d;
    Oth[idx] = hi;
    Otl[idx] = f2bf(val - hf);
  }
}

extern "C" void kernel_launch(void* const* d_in, const int* in_sizes, int n_in,
                              void* d_out, int out_size, void* d_ws, size_t ws_size,
                              hipStream_t stream) {
  const float* xq    = (const float*)d_in[0];
  const float* xkv   = (const float*)d_in[1];
  const float* wqkv  = (const float*)d_in[2];
  const float* wdw   = (const float*)d_in[3];
  const float* wproj = (const float*)d_in[4];
  const float* temp  = (const float*)d_in[5];
  float* out = (float*)d_out;

  char* ws = (char*)d_ws;
  float* t_pre        = (float*)ws;                          // 6 MB
  unsigned short* qb  = (unsigned short*)(ws + 6291456);     // 3 MB
  unsigned short* xt  = (unsigned short*)(ws + 9437184);     // 2 MB
  unsigned short* wq16= (unsigned short*)(ws + 11534336);    // 96 KB
  unsigned short* wph = (unsigned short*)(ws + 11632640);    // 32 KB
  unsigned short* wpl = (unsigned short*)(ws + 11665408);    // 32 KB
  unsigned short* oth = (unsigned short*)(ws + 11698176);    // 1 MB
  unsigned short* otl = (unsigned short*)(ws + 12746752);    // 1 MB

  cast_kernel<<<dim3(260), 256, 0, stream>>>(xq, xkv, wqkv, wproj, xt, wq16, wph, wpl);
  gemm_qkv_kernel<<<dim3(128, 6), 256, 0, stream>>>(xt, wq16, t_pre);
  dwconv_kernel<<<dim3(384), 256, 0, stream>>>(t_pre, wdw, temp, qb);
  attn_kernel<<<dim3(64, 4), 1024, 0, stream>>>(qb, oth, otl);
  gemm_proj_kernel<<<dim3(128, 2), 256, 0, stream>>>(oth, otl, wph, wpl, out);
}